// Round 1
// baseline (872.123 us; speedup 1.0000x reference)
//
#include <hip/hip_runtime.h>
#include <hip/hip_bf16.h>
#include <stdint.h>

#define BATCH 8
#define NPTS  65536
#define CFEAT 256
#define K1    259     // 3 + 256
#define CH    128
#define NS    1024
#define EPSF  1e-5f
#define INVN  (1.0f / (BATCH * NS))

// Order-preserving float<->uint mapping for atomicMax/atomicMin on floats.
__device__ __forceinline__ unsigned fenc(float f) {
  unsigned u = __float_as_uint(f);
  return (u & 0x80000000u) ? ~u : (u | 0x80000000u);
}
__device__ __forceinline__ float fdec(unsigned k) {
  unsigned u = (k & 0x80000000u) ? (k & 0x7fffffffu) : ~k;
  return __uint_as_float(u);
}

// ---------------------------------------------------------------------------
// 1. Selection: per batch, first NS masked indices in ascending order (fill 0)
// ---------------------------------------------------------------------------
__global__ __launch_bounds__(1024) void k_select(const float* __restrict__ xyz,
                                                 int* __restrict__ inds,
                                                 float* __restrict__ center) {
  int b = blockIdx.x;
  int tid = threadIdx.x;
  int lane = tid & 63, wid = tid >> 6;
  const float* xb = xyz + (size_t)b * NPTS * 3;
  float cx = xb[0], cy = xb[1], cz = xb[2];
  if (tid < 3) center[b * 3 + tid] = xb[tid];

  __shared__ int wcnt[16];
  int total = 0;
  int* ib = inds + b * NS;

  for (int base = 0; base < NPTS; base += 1024) {
    int i = base + tid;
    float dx = xb[(size_t)i * 3 + 0] - cx;
    float dy = xb[(size_t)i * 3 + 1] - cy;
    float dz = xb[(size_t)i * 3 + 2] - cz;
    float d2 = dx * dx + dy * dy + dz * dz;
    bool pred = d2 < 1.0f;
    unsigned long long bal = __ballot(pred);
    if (lane == 0) wcnt[wid] = (int)__popcll(bal);
    __syncthreads();
    int woff = 0, itot = 0;
#pragma unroll
    for (int w = 0; w < 16; ++w) {
      int c = wcnt[w];
      if (w < wid) woff += c;
      itot += c;
    }
    int pos = total + woff + (int)__popcll(bal & ((1ull << lane) - 1ull));
    if (pred && pos < NS) ib[pos] = i;
    total += itot;
    __syncthreads();
    if (total >= NS) break;
  }
  for (int j = total + tid; j < NS; j += 1024) ib[j] = 0;
}

// ---------------------------------------------------------------------------
// 2. Gather: G[b][k][n] = (k<3) ? xyz[ids[n]][k]-center : feat[k-3][ids[n]]
//    One block per (b,k) row -> 2072 blocks, full occupancy, BW-bound gather.
// ---------------------------------------------------------------------------
__global__ __launch_bounds__(256) void k_gather(const float* __restrict__ xyz,
                                                const float* __restrict__ feat,
                                                const int* __restrict__ inds,
                                                const float* __restrict__ center,
                                                float* __restrict__ G) {
  int rk = blockIdx.x;           // 0 .. BATCH*K1-1
  int b = rk / K1, k = rk - b * K1;
  const int* ib = inds + b * NS;
  float* gr = G + (size_t)rk * NS;
  if (k < 3) {
    float cv = center[b * 3 + k];
    const float* xb = xyz + (size_t)b * NPTS * 3;
    for (int j = threadIdx.x; j < NS; j += 256)
      gr[j] = xb[(size_t)ib[j] * 3 + k] - cv;
  } else {
    const float* fr = feat + ((size_t)b * CFEAT + (k - 3)) * NPTS;
    for (int j = threadIdx.x; j < NS; j += 256)
      gr[j] = fr[ib[j]];
  }
}

// ---------------------------------------------------------------------------
// Shared epilogue helper: store + per-channel partial BN stats via atomics
// ---------------------------------------------------------------------------
__device__ __forceinline__ void store_and_stats(float* __restrict__ yb,
                                                float* __restrict__ sums,
                                                const float* __restrict__ bias,
                                                float acc[4][4],
                                                int n0, int tx, int ty) {
#pragma unroll
  for (int r = 0; r < 4; ++r) {
    int o = ty * 4 + r;
    float bs = bias[o];
    float4 v = make_float4(acc[r][0] + bs, acc[r][1] + bs,
                           acc[r][2] + bs, acc[r][3] + bs);
    *(float4*)&yb[(size_t)o * NS + n0 + tx * 4] = v;
    float s = v.x + v.y + v.z + v.w;
    float q = v.x * v.x + v.y * v.y + v.z * v.z + v.w * v.w;
    s += __shfl_xor(s, 1, 64); q += __shfl_xor(q, 1, 64);
    s += __shfl_xor(s, 2, 64); q += __shfl_xor(q, 2, 64);
    s += __shfl_xor(s, 4, 64); q += __shfl_xor(q, 4, 64);
    if (tx == 0) {
      atomicAdd(&sums[o], s);
      atomicAdd(&sums[CH + o], q);
    }
  }
}

// ---------------------------------------------------------------------------
// 3. GEMM layer 1 reading the dense gathered panel G.  Tile: 128 x 32.
// ---------------------------------------------------------------------------
__global__ __launch_bounds__(256) void k_gemm1(const float* __restrict__ G,
                                               const float* __restrict__ W,
                                               const float* __restrict__ bias,
                                               float* __restrict__ y,
                                               float* __restrict__ sums) {
  __shared__ float Ws[32][132];
  __shared__ float Xs[32][36];
  int b = blockIdx.y;
  int n0 = blockIdx.x * 32;
  int tid = threadIdx.x;

  int tx = tid & 7, ty = tid >> 3;   // cols tx*4..+3, rows ty*4..+3
  float acc[4][4];
#pragma unroll
  for (int r = 0; r < 4; ++r)
#pragma unroll
    for (int j = 0; j < 4; ++j) acc[r][j] = 0.f;

  const float* Gb = G + (size_t)b * K1 * NS;

  for (int k0 = 0; k0 < K1; k0 += 32) {
    // Ws: 128x32 chunk, coalesced global read (k fast), transposed LDS write
#pragma unroll
    for (int i = 0; i < 16; ++i) {
      int e = tid + 256 * i;
      int o = e >> 5, kk = e & 31;
      int k = k0 + kk;
      Ws[kk][o] = (k < K1) ? W[o * K1 + k] : 0.f;
    }
    // Xs: coalesced read from gathered panel
#pragma unroll
    for (int i = 0; i < 4; ++i) {
      int e = tid + 256 * i;
      int kk = e >> 5, j = e & 31;
      int k = k0 + kk;
      Xs[kk][j] = (k < K1) ? Gb[(size_t)k * NS + n0 + j] : 0.f;
    }
    __syncthreads();
#pragma unroll
    for (int kk = 0; kk < 32; ++kk) {
      float4 xv = *(const float4*)&Xs[kk][tx * 4];
      float4 wv = *(const float4*)&Ws[kk][ty * 4];
      acc[0][0] += wv.x * xv.x; acc[0][1] += wv.x * xv.y; acc[0][2] += wv.x * xv.z; acc[0][3] += wv.x * xv.w;
      acc[1][0] += wv.y * xv.x; acc[1][1] += wv.y * xv.y; acc[1][2] += wv.y * xv.z; acc[1][3] += wv.y * xv.w;
      acc[2][0] += wv.z * xv.x; acc[2][1] += wv.z * xv.y; acc[2][2] += wv.z * xv.z; acc[2][3] += wv.z * xv.w;
      acc[3][0] += wv.w * xv.x; acc[3][1] += wv.w * xv.y; acc[3][2] += wv.w * xv.z; acc[3][3] += wv.w * xv.w;
    }
    __syncthreads();
  }
  store_and_stats(y + (size_t)b * CH * NS, sums, bias, acc, n0, tx, ty);
}

// ---------------------------------------------------------------------------
// 4. GEMM layers 2/3 (K=128). BN+ReLU of the previous layer applied during
//    X staging using sums accumulated by the producer kernel.
//    LAST=true: no y store; track per-(b,channel) max AND min (handles either
//    sign of the BN scale) so layer-3 output never touches HBM.
// ---------------------------------------------------------------------------
template <bool LAST>
__global__ __launch_bounds__(256) void k_gemm23(const float* __restrict__ x,
                                                const float* __restrict__ sums_prev,
                                                const float* __restrict__ gamma,
                                                const float* __restrict__ beta,
                                                const float* __restrict__ W,
                                                const float* __restrict__ bias,
                                                float* __restrict__ y,
                                                float* __restrict__ sums_out,
                                                unsigned* __restrict__ maxk,
                                                unsigned* __restrict__ mink) {
  __shared__ float Ws[32][132];
  __shared__ float Xs[32][36];
  __shared__ float scl[CH], shf[CH];
  int b = blockIdx.y;
  int n0 = blockIdx.x * 32;
  int tid = threadIdx.x;
  if (tid < CH) {
    float s = sums_prev[tid], q = sums_prev[CH + tid];
    float mean = s * INVN;
    float var = fmaxf(q * INVN - mean * mean, 0.f);
    float sc = gamma[tid] * rsqrtf(var + EPSF);
    scl[tid] = sc;
    shf[tid] = beta[tid] - mean * sc;
  }
  __syncthreads();

  int tx = tid & 7, ty = tid >> 3;
  float acc[4][4];
#pragma unroll
  for (int r = 0; r < 4; ++r)
#pragma unroll
    for (int j = 0; j < 4; ++j) acc[r][j] = 0.f;

  const float* xb = x + (size_t)b * CH * NS;

  for (int k0 = 0; k0 < CH; k0 += 32) {
#pragma unroll
    for (int i = 0; i < 16; ++i) {
      int e = tid + 256 * i;
      int o = e >> 5, kk = e & 31;
      Ws[kk][o] = W[o * CH + k0 + kk];
    }
#pragma unroll
    for (int i = 0; i < 4; ++i) {
      int e = tid + 256 * i;
      int kk = e >> 5, j = e & 31;
      int k = k0 + kk;
      float v = xb[(size_t)k * NS + n0 + j];
      Xs[kk][j] = fmaxf(scl[k] * v + shf[k], 0.f);
    }
    __syncthreads();
#pragma unroll
    for (int kk = 0; kk < 32; ++kk) {
      float4 xv = *(const float4*)&Xs[kk][tx * 4];
      float4 wv = *(const float4*)&Ws[kk][ty * 4];
      acc[0][0] += wv.x * xv.x; acc[0][1] += wv.x * xv.y; acc[0][2] += wv.x * xv.z; acc[0][3] += wv.x * xv.w;
      acc[1][0] += wv.y * xv.x; acc[1][1] += wv.y * xv.y; acc[1][2] += wv.y * xv.z; acc[1][3] += wv.y * xv.w;
      acc[2][0] += wv.z * xv.x; acc[2][1] += wv.z * xv.y; acc[2][2] += wv.z * xv.z; acc[2][3] += wv.z * xv.w;
      acc[3][0] += wv.w * xv.x; acc[3][1] += wv.w * xv.y; acc[3][2] += wv.w * xv.z; acc[3][3] += wv.w * xv.w;
    }
    __syncthreads();
  }

  if (!LAST) {
    store_and_stats(y + (size_t)b * CH * NS, sums_out, bias, acc, n0, tx, ty);
  } else {
#pragma unroll
    for (int r = 0; r < 4; ++r) {
      int o = ty * 4 + r;
      float bs = bias[o];
      float4 v = make_float4(acc[r][0] + bs, acc[r][1] + bs,
                             acc[r][2] + bs, acc[r][3] + bs);
      float s = v.x + v.y + v.z + v.w;
      float q = v.x * v.x + v.y * v.y + v.z * v.z + v.w * v.w;
      float mx = fmaxf(fmaxf(v.x, v.y), fmaxf(v.z, v.w));
      float mn = fminf(fminf(v.x, v.y), fminf(v.z, v.w));
      s += __shfl_xor(s, 1, 64); q += __shfl_xor(q, 1, 64);
      mx = fmaxf(mx, __shfl_xor(mx, 1, 64)); mn = fminf(mn, __shfl_xor(mn, 1, 64));
      s += __shfl_xor(s, 2, 64); q += __shfl_xor(q, 2, 64);
      mx = fmaxf(mx, __shfl_xor(mx, 2, 64)); mn = fminf(mn, __shfl_xor(mn, 2, 64));
      s += __shfl_xor(s, 4, 64); q += __shfl_xor(q, 4, 64);
      mx = fmaxf(mx, __shfl_xor(mx, 4, 64)); mn = fminf(mn, __shfl_xor(mn, 4, 64));
      if (tx == 0) {
        atomicAdd(&sums_out[o], s);
        atomicAdd(&sums_out[CH + o], q);
        atomicMax(&maxk[b * CH + o], fenc(mx));
        atomicMin(&mink[b * CH + o], fenc(mn));
      }
    }
  }
}

// ---------------------------------------------------------------------------
// 5. Head MLP. f[b][c] reconstructed from sums3 + per-channel extrema:
//    max_n relu(sc*y+sh) = relu(sc*(sc>=0 ? max_n y : min_n y) + sh).
// ---------------------------------------------------------------------------
__global__ __launch_bounds__(128) void k_head(const float* __restrict__ sums3,
                                              const float* __restrict__ ga3, const float* __restrict__ be3,
                                              const unsigned* __restrict__ maxk, const unsigned* __restrict__ mink,
                                              const float* __restrict__ hw1, const float* __restrict__ hb1,
                                              const float* __restrict__ hg1, const float* __restrict__ hbe1,
                                              const float* __restrict__ hw2, const float* __restrict__ hb2,
                                              const float* __restrict__ hg2, const float* __restrict__ hbe2,
                                              const float* __restrict__ hw3, const float* __restrict__ hb3,
                                              const float* __restrict__ center,
                                              float* __restrict__ out) {
  __shared__ float A[BATCH * 128];
  __shared__ float Bm[BATCH * 128];
  int c = threadIdx.x;
  {
    float s = sums3[c], q = sums3[CH + c];
    float mean = s * INVN;
    float var = fmaxf(q * INVN - mean * mean, 0.f);
    float sc = ga3[c] * rsqrtf(var + EPSF);
    float sh = be3[c] - mean * sc;
#pragma unroll
    for (int b = 0; b < BATCH; ++b) {
      float ymax = fdec(maxk[b * CH + c]);
      float ymin = fdec(mink[b * CH + c]);
      float ye = (sc >= 0.f) ? ymax : ymin;
      A[b * 128 + c] = fmaxf(sc * ye + sh, 0.f);
    }
  }
  __syncthreads();

  {
    float v[BATCH];
    float bs = hb1[c];
#pragma unroll
    for (int b = 0; b < BATCH; ++b) v[b] = bs;
    const float4* w4 = (const float4*)hw1 + c * 32;
    for (int k4 = 0; k4 < 32; ++k4) {
      float4 w = w4[k4];
#pragma unroll
      for (int b = 0; b < BATCH; ++b) {
        const float* Ar = &A[b * 128 + k4 * 4];
        v[b] += Ar[0] * w.x + Ar[1] * w.y + Ar[2] * w.z + Ar[3] * w.w;
      }
    }
    float m = 0.f;
#pragma unroll
    for (int b = 0; b < BATCH; ++b) m += v[b];
    m *= (1.f / BATCH);
    float var = 0.f;
#pragma unroll
    for (int b = 0; b < BATCH; ++b) { float d = v[b] - m; var += d * d; }
    var *= (1.f / BATCH);
    float r = rsqrtf(var + EPSF);
    float ga = hg1[c], be = hbe1[c];
#pragma unroll
    for (int b = 0; b < BATCH; ++b)
      Bm[b * 128 + c] = fmaxf(ga * (v[b] - m) * r + be, 0.f);
  }
  __syncthreads();

  {
    float v[BATCH];
    float bs = hb2[c];
#pragma unroll
    for (int b = 0; b < BATCH; ++b) v[b] = bs;
    const float4* w4 = (const float4*)hw2 + c * 32;
    for (int k4 = 0; k4 < 32; ++k4) {
      float4 w = w4[k4];
#pragma unroll
      for (int b = 0; b < BATCH; ++b) {
        const float* Br = &Bm[b * 128 + k4 * 4];
        v[b] += Br[0] * w.x + Br[1] * w.y + Br[2] * w.z + Br[3] * w.w;
      }
    }
    float m = 0.f;
#pragma unroll
    for (int b = 0; b < BATCH; ++b) m += v[b];
    m *= (1.f / BATCH);
    float var = 0.f;
#pragma unroll
    for (int b = 0; b < BATCH; ++b) { float d = v[b] - m; var += d * d; }
    var *= (1.f / BATCH);
    float r = rsqrtf(var + EPSF);
    float ga = hg2[c], be = hbe2[c];
#pragma unroll
    for (int b = 0; b < BATCH; ++b)
      A[b * 128 + c] = fmaxf(ga * (v[b] - m) * r + be, 0.f);
  }
  __syncthreads();

  if (c < 96) {
    int b = c / 12, j = c % 12;
    float o = hb3[j];
    const float4* w4 = (const float4*)hw3 + j * 32;
    for (int k4 = 0; k4 < 32; ++k4) {
      float4 w = w4[k4];
      const float* Ar = &A[b * 128 + k4 * 4];
      o += Ar[0] * w.x + Ar[1] * w.y + Ar[2] * w.z + Ar[3] * w.w;
    }
    if (j < 3)      out[b * 3 + j] = center[b * 3 + j] + o;
    else if (j < 6) out[24 + b * 3 + (j - 3)] = o;
    else            out[48 + b * 6 + (j - 6)] = o;
  }
}

// ---------------------------------------------------------------------------
extern "C" void kernel_launch(void* const* d_in, const int* in_sizes, int n_in,
                              void* d_out, int out_size, void* d_ws, size_t ws_size,
                              hipStream_t stream) {
  const float* xyz  = (const float*)d_in[0];
  const float* feat = (const float*)d_in[1];
  const float* w1   = (const float*)d_in[2];
  const float* b1   = (const float*)d_in[3];
  const float* ga1  = (const float*)d_in[4];
  const float* be1  = (const float*)d_in[5];
  const float* w2   = (const float*)d_in[6];
  const float* b2   = (const float*)d_in[7];
  const float* ga2  = (const float*)d_in[8];
  const float* be2  = (const float*)d_in[9];
  const float* w3   = (const float*)d_in[10];
  const float* b3   = (const float*)d_in[11];
  const float* ga3  = (const float*)d_in[12];
  const float* be3  = (const float*)d_in[13];
  const float* hw1  = (const float*)d_in[14];
  const float* hb1  = (const float*)d_in[15];
  const float* hg1  = (const float*)d_in[16];
  const float* hbe1 = (const float*)d_in[17];
  const float* hw2  = (const float*)d_in[18];
  const float* hb2  = (const float*)d_in[19];
  const float* hg2  = (const float*)d_in[20];
  const float* hbe2 = (const float*)d_in[21];
  const float* hw3  = (const float*)d_in[22];
  const float* hb3  = (const float*)d_in[23];
  float* out = (float*)d_out;

  char* ws = (char*)d_ws;
  size_t off = 0;
  auto alloc = [&](size_t bytes) -> void* {
    void* p = ws + off;
    off = (off + bytes + 255) & ~(size_t)255;
    return p;
  };
  // zero-init region: sums1..3 then max keys (0 == -NaN key, below all reals)
  float*    sums1 = (float*)alloc(2 * CH * 4);
  float*    sums2 = (float*)alloc(2 * CH * 4);
  float*    sums3 = (float*)alloc(2 * CH * 4);
  unsigned* maxk  = (unsigned*)alloc((size_t)BATCH * CH * 4);
  unsigned* mink  = (unsigned*)alloc((size_t)BATCH * CH * 4);  // init 0xFF
  int*      inds  = (int*)alloc((size_t)BATCH * NS * 4);
  float*    center= (float*)alloc(BATCH * 3 * 4);
  float*    G     = (float*)alloc((size_t)BATCH * K1 * NS * 4);  // 8.5 MB
  float*    y1    = (float*)alloc((size_t)BATCH * CH * NS * 4);  // 4.2 MB
  float*    y2    = (float*)alloc((size_t)BATCH * CH * NS * 4);  // 4.2 MB

  hipMemsetAsync(sums1, 0, (size_t)((char*)mink - (char*)sums1), stream);
  hipMemsetAsync(mink, 0xFF, (size_t)BATCH * CH * 4, stream);

  k_select<<<dim3(BATCH), dim3(1024), 0, stream>>>(xyz, inds, center);
  k_gather<<<dim3(BATCH * K1), dim3(256), 0, stream>>>(xyz, feat, inds, center, G);
  k_gemm1<<<dim3(NS / 32, BATCH), dim3(256), 0, stream>>>(G, w1, b1, y1, sums1);
  k_gemm23<false><<<dim3(NS / 32, BATCH), dim3(256), 0, stream>>>(y1, sums1, ga1, be1,
                                                                  w2, b2, y2, sums2,
                                                                  nullptr, nullptr);
  k_gemm23<true><<<dim3(NS / 32, BATCH), dim3(256), 0, stream>>>(y2, sums2, ga2, be2,
                                                                 w3, b3, nullptr, sums3,
                                                                 maxk, mink);
  k_head<<<dim3(1), dim3(128), 0, stream>>>(sums3, ga3, be3, maxk, mink,
                                            hw1, hb1, hg1, hbe1,
                                            hw2, hb2, hg2, hbe2, hw3, hb3,
                                            center, out);
}

// Round 2
// 851.381 us; speedup vs baseline: 1.0244x; 1.0244x over previous
//
#include <hip/hip_runtime.h>
#include <hip/hip_bf16.h>
#include <stdint.h>

#define BATCH 8
#define NPTS  65536
#define CFEAT 256
#define K1    259     // 3 + 256
#define K1PAD 288     // 9 * 32
#define CH    128
#define NS    1024
#define EPSF  1e-5f
#define INVN  (1.0f / (BATCH * NS))

// Order-preserving float<->uint mapping for atomicMax/atomicMin on floats.
__device__ __forceinline__ unsigned fenc(float f) {
  unsigned u = __float_as_uint(f);
  return (u & 0x80000000u) ? ~u : (u | 0x80000000u);
}
__device__ __forceinline__ float fdec(unsigned k) {
  unsigned u = (k & 0x80000000u) ? (k & 0x7fffffffu) : ~k;
  return __uint_as_float(u);
}

// ---------------------------------------------------------------------------
// 1. Selection: per batch, first NS masked indices in ascending order (fill 0)
//    Block 0 additionally zero-inits the stats/extrema workspace (replaces
//    two hipMemsetAsync dispatches; stream order guarantees visibility).
// ---------------------------------------------------------------------------
__global__ __launch_bounds__(1024) void k_select(const float* __restrict__ xyz,
                                                 int* __restrict__ inds,
                                                 float* __restrict__ center,
                                                 float* __restrict__ sums,   // 3*2*CH floats
                                                 unsigned* __restrict__ maxk,
                                                 unsigned* __restrict__ mink) {
  int b = blockIdx.x;
  int tid = threadIdx.x;
  int lane = tid & 63, wid = tid >> 6;

  if (b == 0) {
    if (tid < 3 * 2 * CH) sums[tid] = 0.f;
    if (tid < BATCH * CH) { maxk[tid] = 0u; mink[tid] = 0xFFFFFFFFu; }
  }

  const float* xb = xyz + (size_t)b * NPTS * 3;
  float cx = xb[0], cy = xb[1], cz = xb[2];
  if (tid < 3) center[b * 3 + tid] = xb[tid];

  __shared__ int wcnt[16];
  int total = 0;
  int* ib = inds + b * NS;

  for (int base = 0; base < NPTS; base += 1024) {
    int i = base + tid;
    float dx = xb[(size_t)i * 3 + 0] - cx;
    float dy = xb[(size_t)i * 3 + 1] - cy;
    float dz = xb[(size_t)i * 3 + 2] - cz;
    float d2 = dx * dx + dy * dy + dz * dz;
    bool pred = d2 < 1.0f;
    unsigned long long bal = __ballot(pred);
    if (lane == 0) wcnt[wid] = (int)__popcll(bal);
    __syncthreads();
    int woff = 0, itot = 0;
#pragma unroll
    for (int w = 0; w < 16; ++w) {
      int c = wcnt[w];
      if (w < wid) woff += c;
      itot += c;
    }
    int pos = total + woff + (int)__popcll(bal & ((1ull << lane) - 1ull));
    if (pred && pos < NS) ib[pos] = i;
    total += itot;
    __syncthreads();
    if (total >= NS) break;
  }
  for (int j = total + tid; j < NS; j += 1024) ib[j] = 0;
}

// ---------------------------------------------------------------------------
// Shared epilogue helper: store + per-channel partial BN stats via atomics
// ---------------------------------------------------------------------------
__device__ __forceinline__ void store_and_stats(float* __restrict__ yb,
                                                float* __restrict__ sums,
                                                const float* __restrict__ bias,
                                                float acc[4][4],
                                                int n0, int tx, int ty) {
#pragma unroll
  for (int r = 0; r < 4; ++r) {
    int o = ty * 4 + r;
    float bs = bias[o];
    float4 v = make_float4(acc[r][0] + bs, acc[r][1] + bs,
                           acc[r][2] + bs, acc[r][3] + bs);
    *(float4*)&yb[(size_t)o * NS + n0 + tx * 4] = v;
    float s = v.x + v.y + v.z + v.w;
    float q = v.x * v.x + v.y * v.y + v.z * v.z + v.w * v.w;
    s += __shfl_xor(s, 1, 64); q += __shfl_xor(q, 1, 64);
    s += __shfl_xor(s, 2, 64); q += __shfl_xor(q, 2, 64);
    s += __shfl_xor(s, 4, 64); q += __shfl_xor(q, 4, 64);
    if (tx == 0) {
      atomicAdd(&sums[o], s);
      atomicAdd(&sums[CH + o], q);
    }
  }
}

// ---------------------------------------------------------------------------
// 2. GEMM layer 1, gather fused. The FULL 259x32 X-tile is staged into LDS
//    up front: 8288 independent scattered loads issued by all 256 threads
//    before one barrier (latency hidden by ILP), then the K-loop only
//    re-stages 32-row W chunks. Rows 259..287 zeroed so the inner loop is
//    branch-free over 9 full chunks.
// ---------------------------------------------------------------------------
__global__ __launch_bounds__(256) void k_gemm1(const float* __restrict__ xyz,
                                               const float* __restrict__ feat,
                                               const int* __restrict__ inds,
                                               const float* __restrict__ center,
                                               const float* __restrict__ W,
                                               const float* __restrict__ bias,
                                               float* __restrict__ y,
                                               float* __restrict__ sums) {
  __shared__ float Ws[32][132];     // 16.9 KB
  __shared__ float Xs[K1PAD][36];   // 41.5 KB
  __shared__ int   ids[32];
  __shared__ float cenl[3];
  int b = blockIdx.y;
  int n0 = blockIdx.x * 32;
  int tid = threadIdx.x;
  if (tid < 32) ids[tid] = inds[b * NS + n0 + tid];
  if (tid < 3)  cenl[tid] = center[b * 3 + tid];
  __syncthreads();

  const float* featb = feat + (size_t)b * CFEAT * NPTS;
  const float* xyzb  = xyz + (size_t)b * NPTS * 3;

  // xyz rows (k = 0..2)
  if (tid < 96) {
    int k = tid >> 5, j = tid & 31;
    Xs[k][j] = xyzb[(size_t)ids[j] * 3 + k] - cenl[k];
  }
  // feature rows (k = 3..258): 8192 independent scattered loads
#pragma unroll 8
  for (int e = tid; e < CFEAT * 32; e += 256) {
    int k = e >> 5, j = e & 31;
    Xs[3 + k][j] = featb[(size_t)k * NPTS + ids[j]];
  }
  // zero pad rows 259..287
#pragma unroll
  for (int e = tid; e < 29 * 32; e += 256) {
    Xs[K1 + (e >> 5)][e & 31] = 0.f;
  }

  int tx = tid & 7, ty = tid >> 3;   // cols tx*4..+3, rows ty*4..+3
  float acc[4][4];
#pragma unroll
  for (int r = 0; r < 4; ++r)
#pragma unroll
    for (int j = 0; j < 4; ++j) acc[r][j] = 0.f;

  for (int k0 = 0; k0 < K1PAD; k0 += 32) {
    // Ws: 128x32 chunk, coalesced global read (k fast), transposed LDS write
#pragma unroll
    for (int i = 0; i < 16; ++i) {
      int e = tid + 256 * i;
      int o = e >> 5, kk = e & 31;
      int k = k0 + kk;
      Ws[kk][o] = (k < K1) ? W[o * K1 + k] : 0.f;
    }
    __syncthreads();
#pragma unroll
    for (int kk = 0; kk < 32; ++kk) {
      float4 xv = *(const float4*)&Xs[k0 + kk][tx * 4];
      float4 wv = *(const float4*)&Ws[kk][ty * 4];
      acc[0][0] += wv.x * xv.x; acc[0][1] += wv.x * xv.y; acc[0][2] += wv.x * xv.z; acc[0][3] += wv.x * xv.w;
      acc[1][0] += wv.y * xv.x; acc[1][1] += wv.y * xv.y; acc[1][2] += wv.y * xv.z; acc[1][3] += wv.y * xv.w;
      acc[2][0] += wv.z * xv.x; acc[2][1] += wv.z * xv.y; acc[2][2] += wv.z * xv.z; acc[2][3] += wv.z * xv.w;
      acc[3][0] += wv.w * xv.x; acc[3][1] += wv.w * xv.y; acc[3][2] += wv.w * xv.z; acc[3][3] += wv.w * xv.w;
    }
    __syncthreads();
  }
  store_and_stats(y + (size_t)b * CH * NS, sums, bias, acc, n0, tx, ty);
}

// ---------------------------------------------------------------------------
// 3. GEMM layers 2/3 (K=128). BN+ReLU of the previous layer applied during
//    X staging (full tile staged once). LAST=true: no y store; track
//    per-(b,channel) max AND min so layer-3 output never touches HBM.
// ---------------------------------------------------------------------------
template <bool LAST>
__global__ __launch_bounds__(256) void k_gemm23(const float* __restrict__ x,
                                                const float* __restrict__ sums_prev,
                                                const float* __restrict__ gamma,
                                                const float* __restrict__ beta,
                                                const float* __restrict__ W,
                                                const float* __restrict__ bias,
                                                float* __restrict__ y,
                                                float* __restrict__ sums_out,
                                                unsigned* __restrict__ maxk,
                                                unsigned* __restrict__ mink) {
  __shared__ float Ws[32][132];
  __shared__ float Xs[CH][36];
  __shared__ float scl[CH], shf[CH];
  int b = blockIdx.y;
  int n0 = blockIdx.x * 32;
  int tid = threadIdx.x;
  if (tid < CH) {
    float s = sums_prev[tid], q = sums_prev[CH + tid];
    float mean = s * INVN;
    float var = fmaxf(q * INVN - mean * mean, 0.f);
    float sc = gamma[tid] * rsqrtf(var + EPSF);
    scl[tid] = sc;
    shf[tid] = beta[tid] - mean * sc;
  }
  __syncthreads();

  const float* xb = x + (size_t)b * CH * NS;
  // stage full 128x32 X tile with BN+ReLU applied
#pragma unroll
  for (int e = tid; e < CH * 32; e += 256) {
    int k = e >> 5, j = e & 31;
    float v = xb[(size_t)k * NS + n0 + j];
    Xs[k][j] = fmaxf(scl[k] * v + shf[k], 0.f);
  }

  int tx = tid & 7, ty = tid >> 3;
  float acc[4][4];
#pragma unroll
  for (int r = 0; r < 4; ++r)
#pragma unroll
    for (int j = 0; j < 4; ++j) acc[r][j] = 0.f;

  for (int k0 = 0; k0 < CH; k0 += 32) {
#pragma unroll
    for (int i = 0; i < 16; ++i) {
      int e = tid + 256 * i;
      int o = e >> 5, kk = e & 31;
      Ws[kk][o] = W[o * CH + k0 + kk];
    }
    __syncthreads();
#pragma unroll
    for (int kk = 0; kk < 32; ++kk) {
      float4 xv = *(const float4*)&Xs[k0 + kk][tx * 4];
      float4 wv = *(const float4*)&Ws[kk][ty * 4];
      acc[0][0] += wv.x * xv.x; acc[0][1] += wv.x * xv.y; acc[0][2] += wv.x * xv.z; acc[0][3] += wv.x * xv.w;
      acc[1][0] += wv.y * xv.x; acc[1][1] += wv.y * xv.y; acc[1][2] += wv.y * xv.z; acc[1][3] += wv.y * xv.w;
      acc[2][0] += wv.z * xv.x; acc[2][1] += wv.z * xv.y; acc[2][2] += wv.z * xv.z; acc[2][3] += wv.z * xv.w;
      acc[3][0] += wv.w * xv.x; acc[3][1] += wv.w * xv.y; acc[3][2] += wv.w * xv.z; acc[3][3] += wv.w * xv.w;
    }
    __syncthreads();
  }

  if (!LAST) {
    store_and_stats(y + (size_t)b * CH * NS, sums_out, bias, acc, n0, tx, ty);
  } else {
#pragma unroll
    for (int r = 0; r < 4; ++r) {
      int o = ty * 4 + r;
      float bs = bias[o];
      float4 v = make_float4(acc[r][0] + bs, acc[r][1] + bs,
                             acc[r][2] + bs, acc[r][3] + bs);
      float s = v.x + v.y + v.z + v.w;
      float q = v.x * v.x + v.y * v.y + v.z * v.z + v.w * v.w;
      float mx = fmaxf(fmaxf(v.x, v.y), fmaxf(v.z, v.w));
      float mn = fminf(fminf(v.x, v.y), fminf(v.z, v.w));
      s += __shfl_xor(s, 1, 64); q += __shfl_xor(q, 1, 64);
      mx = fmaxf(mx, __shfl_xor(mx, 1, 64)); mn = fminf(mn, __shfl_xor(mn, 1, 64));
      s += __shfl_xor(s, 2, 64); q += __shfl_xor(q, 2, 64);
      mx = fmaxf(mx, __shfl_xor(mx, 2, 64)); mn = fminf(mn, __shfl_xor(mn, 2, 64));
      s += __shfl_xor(s, 4, 64); q += __shfl_xor(q, 4, 64);
      mx = fmaxf(mx, __shfl_xor(mx, 4, 64)); mn = fminf(mn, __shfl_xor(mn, 4, 64));
      if (tx == 0) {
        atomicAdd(&sums_out[o], s);
        atomicAdd(&sums_out[CH + o], q);
        atomicMax(&maxk[b * CH + o], fenc(mx));
        atomicMin(&mink[b * CH + o], fenc(mn));
      }
    }
  }
}

// ---------------------------------------------------------------------------
// 4. Head MLP. f[b][c] reconstructed from sums3 + per-channel extrema:
//    max_n relu(sc*y+sh) = relu(sc*(sc>=0 ? max_n y : min_n y) + sh).
// ---------------------------------------------------------------------------
__global__ __launch_bounds__(128) void k_head(const float* __restrict__ sums3,
                                              const float* __restrict__ ga3, const float* __restrict__ be3,
                                              const unsigned* __restrict__ maxk, const unsigned* __restrict__ mink,
                                              const float* __restrict__ hw1, const float* __restrict__ hb1,
                                              const float* __restrict__ hg1, const float* __restrict__ hbe1,
                                              const float* __restrict__ hw2, const float* __restrict__ hb2,
                                              const float* __restrict__ hg2, const float* __restrict__ hbe2,
                                              const float* __restrict__ hw3, const float* __restrict__ hb3,
                                              const float* __restrict__ center,
                                              float* __restrict__ out) {
  __shared__ float A[BATCH * 128];
  __shared__ float Bm[BATCH * 128];
  int c = threadIdx.x;
  {
    float s = sums3[c], q = sums3[CH + c];
    float mean = s * INVN;
    float var = fmaxf(q * INVN - mean * mean, 0.f);
    float sc = ga3[c] * rsqrtf(var + EPSF);
    float sh = be3[c] - mean * sc;
#pragma unroll
    for (int b = 0; b < BATCH; ++b) {
      float ymax = fdec(maxk[b * CH + c]);
      float ymin = fdec(mink[b * CH + c]);
      float ye = (sc >= 0.f) ? ymax : ymin;
      A[b * 128 + c] = fmaxf(sc * ye + sh, 0.f);
    }
  }
  __syncthreads();

  {
    float v[BATCH];
    float bs = hb1[c];
#pragma unroll
    for (int b = 0; b < BATCH; ++b) v[b] = bs;
    const float4* w4 = (const float4*)hw1 + c * 32;
    for (int k4 = 0; k4 < 32; ++k4) {
      float4 w = w4[k4];
#pragma unroll
      for (int b = 0; b < BATCH; ++b) {
        const float* Ar = &A[b * 128 + k4 * 4];
        v[b] += Ar[0] * w.x + Ar[1] * w.y + Ar[2] * w.z + Ar[3] * w.w;
      }
    }
    float m = 0.f;
#pragma unroll
    for (int b = 0; b < BATCH; ++b) m += v[b];
    m *= (1.f / BATCH);
    float var = 0.f;
#pragma unroll
    for (int b = 0; b < BATCH; ++b) { float d = v[b] - m; var += d * d; }
    var *= (1.f / BATCH);
    float r = rsqrtf(var + EPSF);
    float ga = hg1[c], be = hbe1[c];
#pragma unroll
    for (int b = 0; b < BATCH; ++b)
      Bm[b * 128 + c] = fmaxf(ga * (v[b] - m) * r + be, 0.f);
  }
  __syncthreads();

  {
    float v[BATCH];
    float bs = hb2[c];
#pragma unroll
    for (int b = 0; b < BATCH; ++b) v[b] = bs;
    const float4* w4 = (const float4*)hw2 + c * 32;
    for (int k4 = 0; k4 < 32; ++k4) {
      float4 w = w4[k4];
#pragma unroll
      for (int b = 0; b < BATCH; ++b) {
        const float* Br = &Bm[b * 128 + k4 * 4];
        v[b] += Br[0] * w.x + Br[1] * w.y + Br[2] * w.z + Br[3] * w.w;
      }
    }
    float m = 0.f;
#pragma unroll
    for (int b = 0; b < BATCH; ++b) m += v[b];
    m *= (1.f / BATCH);
    float var = 0.f;
#pragma unroll
    for (int b = 0; b < BATCH; ++b) { float d = v[b] - m; var += d * d; }
    var *= (1.f / BATCH);
    float r = rsqrtf(var + EPSF);
    float ga = hg2[c], be = hbe2[c];
#pragma unroll
    for (int b = 0; b < BATCH; ++b)
      A[b * 128 + c] = fmaxf(ga * (v[b] - m) * r + be, 0.f);
  }
  __syncthreads();

  if (c < 96) {
    int b = c / 12, j = c % 12;
    float o = hb3[j];
    const float4* w4 = (const float4*)hw3 + j * 32;
    for (int k4 = 0; k4 < 32; ++k4) {
      float4 w = w4[k4];
      const float* Ar = &A[b * 128 + k4 * 4];
      o += Ar[0] * w.x + Ar[1] * w.y + Ar[2] * w.z + Ar[3] * w.w;
    }
    if (j < 3)      out[b * 3 + j] = center[b * 3 + j] + o;
    else if (j < 6) out[24 + b * 3 + (j - 3)] = o;
    else            out[48 + b * 6 + (j - 6)] = o;
  }
}

// ---------------------------------------------------------------------------
extern "C" void kernel_launch(void* const* d_in, const int* in_sizes, int n_in,
                              void* d_out, int out_size, void* d_ws, size_t ws_size,
                              hipStream_t stream) {
  const float* xyz  = (const float*)d_in[0];
  const float* feat = (const float*)d_in[1];
  const float* w1   = (const float*)d_in[2];
  const float* b1   = (const float*)d_in[3];
  const float* ga1  = (const float*)d_in[4];
  const float* be1  = (const float*)d_in[5];
  const float* w2   = (const float*)d_in[6];
  const float* b2   = (const float*)d_in[7];
  const float* ga2  = (const float*)d_in[8];
  const float* be2  = (const float*)d_in[9];
  const float* w3   = (const float*)d_in[10];
  const float* b3   = (const float*)d_in[11];
  const float* ga3  = (const float*)d_in[12];
  const float* be3  = (const float*)d_in[13];
  const float* hw1  = (const float*)d_in[14];
  const float* hb1  = (const float*)d_in[15];
  const float* hg1  = (const float*)d_in[16];
  const float* hbe1 = (const float*)d_in[17];
  const float* hw2  = (const float*)d_in[18];
  const float* hb2  = (const float*)d_in[19];
  const float* hg2  = (const float*)d_in[20];
  const float* hbe2 = (const float*)d_in[21];
  const float* hw3  = (const float*)d_in[22];
  const float* hb3  = (const float*)d_in[23];
  float* out = (float*)d_out;

  char* ws = (char*)d_ws;
  size_t off = 0;
  auto alloc = [&](size_t bytes) -> void* {
    void* p = ws + off;
    off = (off + bytes + 255) & ~(size_t)255;
    return p;
  };
  // sums1|sums2|sums3 contiguous (k_select zero-inits all three as one array)
  float*    sums1 = (float*)alloc(2 * CH * 4);
  float*    sums2 = (float*)alloc(2 * CH * 4);
  float*    sums3 = (float*)alloc(2 * CH * 4);
  unsigned* maxk  = (unsigned*)alloc((size_t)BATCH * CH * 4);
  unsigned* mink  = (unsigned*)alloc((size_t)BATCH * CH * 4);
  int*      inds  = (int*)alloc((size_t)BATCH * NS * 4);
  float*    center= (float*)alloc(BATCH * 3 * 4);
  float*    y1    = (float*)alloc((size_t)BATCH * CH * NS * 4);  // 4.2 MB
  float*    y2    = (float*)alloc((size_t)BATCH * CH * NS * 4);  // 4.2 MB

  k_select<<<dim3(BATCH), dim3(1024), 0, stream>>>(xyz, inds, center,
                                                   sums1, maxk, mink);
  k_gemm1<<<dim3(NS / 32, BATCH), dim3(256), 0, stream>>>(xyz, feat, inds, center,
                                                          w1, b1, y1, sums1);
  k_gemm23<false><<<dim3(NS / 32, BATCH), dim3(256), 0, stream>>>(y1, sums1, ga1, be1,
                                                                  w2, b2, y2, sums2,
                                                                  nullptr, nullptr);
  k_gemm23<true><<<dim3(NS / 32, BATCH), dim3(256), 0, stream>>>(y2, sums2, ga2, be2,
                                                                 w3, b3, nullptr, sums3,
                                                                 maxk, mink);
  k_head<<<dim3(1), dim3(128), 0, stream>>>(sums3, ga3, be3, maxk, mink,
                                            hw1, hb1, hg1, hbe1,
                                            hw2, hb2, hg2, hbe2, hw3, hb3,
                                            center, out);
}